// Round 5
// baseline (185.019 us; speedup 1.0000x reference)
//
#include <hip/hip_runtime.h>

#define K_OFF 27
#define CIN   2
#define COUT  16
#define PTS   128            // points per block
#define KG    7              // k-slots per group (group 3 has 6 real + 1 dummy)
#define ROWF  52             // LDS row: 3*16 floats + 4 pad = 208 B (13 * 16B -> conflict-free b128)

__global__ __launch_bounds__(512, 8) void spconv_kernel(
    const float* __restrict__ feats,   // [N][2]
    const float* __restrict__ w,       // [27][2][16]
    const int*   __restrict__ nbr,     // [N][27]
    float*       __restrict__ out,     // [N][16]
    int n_pts)
{
    __shared__ float s_red[PTS * ROWF];          // 26624 B

    const int t     = threadIdx.x;
    const int p_loc = t & (PTS - 1);             // 0..127
    const int g     = t >> 7;                    // 0..3, wave-uniform
    const int p     = blockIdx.x * PTS + p_loc;
    const bool pvalid = (p < n_pts);

    const int k0 = g * KG;                       // 0,7,14,21
    const int nk = (g == 3) ? 6 : KG;            // wave-uniform

    const float2* feats2 = reinterpret_cast<const float2*>(feats);

    // ---- batched idx read + clamped gather (7 independent loads in flight) ----
    float2 f[KG];
    float  m[KG];
    const int base = p * K_OFF + k0;
    #pragma unroll
    for (int j = 0; j < KG; ++j) {
        int idx = -1;
        if (pvalid && j < nk) idx = nbr[base + j];
        m[j] = (idx >= 0) ? 1.0f : 0.0f;
        f[j] = feats2[idx > 0 ? idx : 0];        // invalid lanes broadcast line 0
    }

    float acc[COUT];
    #pragma unroll
    for (int d = 0; d < COUT; ++d) acc[d] = 0.f;

    #pragma unroll
    for (int j = 0; j < KG; ++j) {
        const float fx = f[j].x * m[j];
        const float fy = f[j].y * m[j];
        const int   kk = (k0 + j < K_OFF) ? (k0 + j) : 0;   // dummy slot: m=0, safe w row
        const float* wk = w + kk * (CIN * COUT);            // wave-uniform -> s_load
        #pragma unroll
        for (int d = 0; d < COUT; ++d) {
            acc[d] = fmaf(fx, wk[d],        acc[d]);
            acc[d] = fmaf(fy, wk[COUT + d], acc[d]);
        }
    }

    // ---- 4 -> 1 reduction via LDS (groups 1..3 write partials, group 0 sums) ----
    if (g != 0) {
        float4* dst = reinterpret_cast<float4*>(s_red + p_loc * ROWF + (g - 1) * COUT);
        dst[0] = make_float4(acc[0],  acc[1],  acc[2],  acc[3]);
        dst[1] = make_float4(acc[4],  acc[5],  acc[6],  acc[7]);
        dst[2] = make_float4(acc[8],  acc[9],  acc[10], acc[11]);
        dst[3] = make_float4(acc[12], acc[13], acc[14], acc[15]);
    }
    __syncthreads();

    if (g == 0 && pvalid) {
        const float* row = s_red + p_loc * ROWF;
        #pragma unroll
        for (int gg = 0; gg < 3; ++gg) {
            #pragma unroll
            for (int d = 0; d < COUT; ++d)
                acc[d] += row[gg * COUT + d];
        }
        float4* o = reinterpret_cast<float4*>(out + (size_t)p * COUT);
        o[0] = make_float4(acc[0],  acc[1],  acc[2],  acc[3]);
        o[1] = make_float4(acc[4],  acc[5],  acc[6],  acc[7]);
        o[2] = make_float4(acc[8],  acc[9],  acc[10], acc[11]);
        o[3] = make_float4(acc[12], acc[13], acc[14], acc[15]);
    }
}

extern "C" void kernel_launch(void* const* d_in, const int* in_sizes, int n_in,
                              void* d_out, int out_size, void* d_ws, size_t ws_size,
                              hipStream_t stream) {
    const float* feats = (const float*)d_in[0];
    const float* w     = (const float*)d_in[1];
    const int*   nbr   = (const int*)d_in[2];
    float*       out   = (float*)d_out;

    const int n_pts = in_sizes[0] / CIN;
    const int grid  = (n_pts + PTS - 1) / PTS;

    spconv_kernel<<<grid, 512, 0, stream>>>(feats, w, nbr, out, n_pts);
}

// Round 6
// 54.185 us; speedup vs baseline: 3.4146x; 3.4146x over previous
//
#include <hip/hip_runtime.h>

#define K_OFF 27
#define CIN   2
#define COUT  16
#define BLK   256
#define WPB   4                 // waves per block
#define IPW   (64 * K_OFF)      // 1728 ints per wave tile

typedef __attribute__((address_space(3))) unsigned int lds_u32;
typedef __attribute__((address_space(1))) const unsigned int g_u32;

__global__ __launch_bounds__(BLK, 4) void spconv_kernel(
    const float* __restrict__ feats,   // [N][2]
    const float* __restrict__ w,       // [27][2][16]
    const int*   __restrict__ nbr,     // [N][27]
    float*       __restrict__ out,     // [N][16]
    int n_pts)
{
    __shared__ int    s_idx[WPB * IPW];   // 27648 B, wave-private staging
    __shared__ float4 s_w[8 * K_OFF];     // 3456 B, W as [q][k] float4

    const int t    = threadIdx.x;
    const int lane = t & 63;
    const int wv   = t >> 6;
    const int tile = blockIdx.x * WPB + wv;
    const int p    = tile * 64 + lane;

    // ---- W -> LDS, [q][k] layout (q = float4 chunk: q<4 -> cin0, q>=4 -> cin1) ----
    if (t < 8 * K_OFF) {
        const int k = t >> 3, q = t & 7;
        s_w[q * K_OFF + k] = reinterpret_cast<const float4*>(w)[t];  // src f4 idx = k*8+q = t
    }

    const bool full = ((tile + 1) * 64 <= n_pts);   // wave-uniform
    if (full) {
        // async coalesced stage: HBM -> LDS, no VGPR round-trip
        const int* src = nbr + (size_t)tile * IPW;
        int*       dst = s_idx + wv * IPW;
        #pragma unroll
        for (int j = 0; j < 6; ++j) {
            __builtin_amdgcn_global_load_lds(
                (g_u32*)(src + j * 256 + lane * 4),
                (lds_u32*)(dst + j * 256), 16, 0, 0);
        }
        if (lane < 48) {   // remainder: 192 ints
            __builtin_amdgcn_global_load_lds(
                (g_u32*)(src + 6 * 256 + lane * 4),
                (lds_u32*)(dst + 6 * 256), 16, 0, 0);
        }
    }
    __syncthreads();   // drains vmcnt (stage) + lgkm (W writes)

    float acc[COUT];
    #pragma unroll
    for (int d = 0; d < COUT; ++d) acc[d] = 0.f;

    const float2* feats2 = reinterpret_cast<const float2*>(feats);
    const int* rowp = s_idx + wv * IPW + lane * K_OFF;

    // ---- scan: per-lane validity bitmap (27 batched ds_reads, stride-27 conflict-free) ----
    unsigned bm = 0;
    if (full) {
        #pragma unroll
        for (int k = 0; k < K_OFF; ++k)
            bm |= (rowp[k] >= 0) ? (1u << k) : 0u;
    }

    // wave-max trip count
    int mx = __popc(bm);
    #pragma unroll
    for (int off = 32; off; off >>= 1) mx = max(mx, __shfl_xor(mx, off, 64));

    // ---- compacted pair loop: ~2.6 avg (max ~9) instead of 27 ----
    #pragma unroll 2
    for (int j = 0; j < mx; ++j) {
        const bool alive = (bm != 0);
        const unsigned kk = __builtin_ctz(bm | 0x80000000u);  // defined for bm==0
        const int k = alive ? (int)kk : 0;
        bm &= bm - 1;
        const int idx_raw = rowp[k];                 // per-lane k: permuted banks
        const int idx = alive ? idx_raw : 0;         // dead lanes broadcast line 0
        const float2 f = feats2[idx];
        const float fm = alive ? 1.0f : 0.0f;
        const float fx = f.x * fm, fy = f.y * fm;
        #pragma unroll
        for (int q = 0; q < 4; ++q) {
            const float4 wa = s_w[q * K_OFF + k];        // cin=0, d=4q..4q+3
            const float4 wb = s_w[(q + 4) * K_OFF + k];  // cin=1
            acc[q*4+0] = fmaf(fy, wb.x, fmaf(fx, wa.x, acc[q*4+0]));
            acc[q*4+1] = fmaf(fy, wb.y, fmaf(fx, wa.y, acc[q*4+1]));
            acc[q*4+2] = fmaf(fy, wb.z, fmaf(fx, wa.z, acc[q*4+2]));
            acc[q*4+3] = fmaf(fy, wb.w, fmaf(fx, wa.w, acc[q*4+3]));
        }
    }

    // ---- partial-tile fallback: dense masked loop, direct global idx reads ----
    if (!full) {
        const bool pv = (p < n_pts);
        for (int k = 0; k < K_OFF; ++k) {
            const int idx = pv ? nbr[(size_t)p * K_OFF + k] : -1;
            const float fm = (idx >= 0) ? 1.0f : 0.0f;
            const float2 f = feats2[idx > 0 ? idx : 0];
            const float fx = f.x * fm, fy = f.y * fm;
            #pragma unroll
            for (int q = 0; q < 4; ++q) {
                const float4 wa = s_w[q * K_OFF + k];
                const float4 wb = s_w[(q + 4) * K_OFF + k];
                acc[q*4+0] = fmaf(fy, wb.x, fmaf(fx, wa.x, acc[q*4+0]));
                acc[q*4+1] = fmaf(fy, wb.y, fmaf(fx, wa.y, acc[q*4+1]));
                acc[q*4+2] = fmaf(fy, wb.z, fmaf(fx, wa.z, acc[q*4+2]));
                acc[q*4+3] = fmaf(fy, wb.w, fmaf(fx, wa.w, acc[q*4+3]));
            }
        }
    }

    if (p < n_pts) {
        float4* o = reinterpret_cast<float4*>(out + (size_t)p * COUT);
        o[0] = make_float4(acc[0],  acc[1],  acc[2],  acc[3]);
        o[1] = make_float4(acc[4],  acc[5],  acc[6],  acc[7]);
        o[2] = make_float4(acc[8],  acc[9],  acc[10], acc[11]);
        o[3] = make_float4(acc[12], acc[13], acc[14], acc[15]);
    }
}

extern "C" void kernel_launch(void* const* d_in, const int* in_sizes, int n_in,
                              void* d_out, int out_size, void* d_ws, size_t ws_size,
                              hipStream_t stream) {
    const float* feats = (const float*)d_in[0];
    const float* w     = (const float*)d_in[1];
    const int*   nbr   = (const int*)d_in[2];
    float*       out   = (float*)d_out;

    const int n_pts   = in_sizes[0] / CIN;
    const int n_tiles = (n_pts + 63) / 64;
    const int grid    = (n_tiles + WPB - 1) / WPB;

    spconv_kernel<<<grid, BLK, 0, stream>>>(feats, w, nbr, out, n_pts);
}